// Round 16
// baseline (241.645 us; speedup 1.0000x reference)
//
#include <hip/hip_runtime.h>
#include <cmath>

#define NCC 151
#define NRCH 51
#define BDIM 32
#define NOBJ 100
#define DDIM 4096
#define HDIM 1024
#define TDIM (BDIM * NOBJ)   // 3200
#define NPAIR (NCC * NCC)    // 22801

typedef __bf16 bf16_t;
typedef __bf16 bf16x8 __attribute__((ext_vector_type(8)));
typedef __bf16 bf16x4 __attribute__((ext_vector_type(4)));
typedef float f32x4 __attribute__((ext_vector_type(4)));

// ---------------------------------------------------------------------------
// bf16 MFMA GEMM, PIPELINED dbuf (R16): C = act(A @ Bt^T) (+ add)
// 128x128 tile, BK=64, 256 threads = 4 waves (2x2), 16x16x32 MFMA.
// K-loop: stage(next) -> compute(cur) -> asm vmcnt(0) -> RAW s_barrier.
// Unlike R9 (__syncthreads = compiler drains vmcnt BEFORE compute), the
// drain here lands AFTER the MFMA block, hiding staging latency — the
// only latency hider at this kernel's 1-2 blocks/CU occupancy.
// XOR-swizzled LDS. MODE 0: bijective XCD-chunk swizzle (nwg % 8 == 0).
// MODE 3 (G1, SPLITK=4, grid 832 flat): XCD-pair owns one K=1024 plane.
// SPLITK>1: bf16 partial to Cout + bz*MN. ADDBF16: fp32 out = relu + add.
// ---------------------------------------------------------------------------
template <bool RELU, bool ADDBF16, int SPLITK, int MODE>
__global__ __launch_bounds__(256) void gemm_bf16(
    const bf16_t* __restrict__ A, const bf16_t* __restrict__ Bt,
    const bf16_t* __restrict__ add, void* __restrict__ Cout,
    int N, int K, size_t MN) {
  __shared__ __align__(16) bf16_t Asm[2][128 * 64];
  __shared__ __align__(16) bf16_t Bsm[2][128 * 64];
  const int tid = threadIdx.x;
  const int lane = tid & 63;
  const int w = tid >> 6;
  const int wm = w >> 1, wn = w & 1;

  const int nx = gridDim.x, ny = gridDim.y, nz = gridDim.z;
  const int h = blockIdx.x + nx * (blockIdx.y + ny * blockIdx.z);
  int bx, by, bz;
  if (MODE == 3) {
    const int xcd = h & 7, s = h >> 3;   // s in [0,104)
    bz = xcd >> 1;
    const int half = xcd & 1;
    if (half == 1 && s >= 96) return;    // idle pad blocks (block-uniform)
    const int c = s / 40;
    if (c < 2) {
      const int within = s % 40;
      bx = within / 5;
      by = (half ? 13 : 0) + c * 5 + within % 5;
    } else if (half == 0) {
      const int w2 = s - 80;
      bx = w2 / 3;
      by = 10 + w2 % 3;
    } else {
      const int w2 = s - 80;
      bx = w2 / 2;
      by = 23 + w2 % 2;
    }
  } else {
    const int nwg = nx * ny * nz;  // % 8 == 0
    const int q = nwg >> 3;
    const int lin = (h & 7) * q + (h >> 3);
    by = lin % ny;
    const int r = lin / ny;
    bx = r % nx;
    bz = r / nx;
  }

  const int bm = by * 128, bn = bx * 128;
  const int lr = lane & 15, lk = lane >> 4;

  int kBeg = 0, kEnd = K;
  if (SPLITK > 1) {
    const int chunk = (((K / 64) + SPLITK - 1) / SPLITK) * 64;
    kBeg = bz * chunk;
    kEnd = min(K, kBeg + chunk);
  }

  f32x4 acc[4][4];
#pragma unroll
  for (int m = 0; m < 4; ++m)
#pragma unroll
    for (int n = 0; n < 4; ++n) acc[m][n] = (f32x4){0.f, 0.f, 0.f, 0.f};

  const int srow = tid >> 3, sslot = tid & 7;

  auto stage = [&](int buf, int kt) {
#pragma unroll
    for (int i = 0; i < 4; ++i) {
      const int row = i * 32 + srow;
      const int kc = sslot ^ (row & 7);
      const bf16_t* ga = A + (size_t)(bm + row) * K + kt + kc * 8;
      const bf16_t* gb = Bt + (size_t)(bn + row) * K + kt + kc * 8;
      __builtin_amdgcn_global_load_lds(
          (const __attribute__((address_space(1))) void*)ga,
          (__attribute__((address_space(3))) void*)((char*)&Asm[buf][0] +
                                                    i * 4096 + w * 1024),
          16, 0, 0);
      __builtin_amdgcn_global_load_lds(
          (const __attribute__((address_space(1))) void*)gb,
          (__attribute__((address_space(3))) void*)((char*)&Bsm[buf][0] +
                                                    i * 4096 + w * 1024),
          16, 0, 0);
    }
  };

  // prologue: fill buf 0, drain, raw barrier
  stage(0, kBeg);
  asm volatile("s_waitcnt vmcnt(0)" ::: "memory");
  __builtin_amdgcn_s_barrier();

  int cur = 0;
  for (int kt = kBeg; kt < kEnd; kt += 64) {
    const bool more = (kt + 64 < kEnd);
    if (more) stage(cur ^ 1, kt + 64);  // issue next-tile loads EARLY

    char* ldsA = (char*)&Asm[cur][0];
    char* ldsB = (char*)&Bsm[cur][0];
    bf16x8 af[4][2], bfr[4][2];
#pragma unroll
    for (int m = 0; m < 4; ++m) {
      const int row = wm * 64 + m * 16 + lr;
#pragma unroll
      for (int kk = 0; kk < 2; ++kk) {
        const int slot = kk * 4 + lk;
        af[m][kk] =
            *(const bf16x8*)(ldsA + row * 128 + ((slot ^ (lr & 7)) << 4));
      }
    }
#pragma unroll
    for (int n = 0; n < 4; ++n) {
      const int row = wn * 64 + n * 16 + lr;
#pragma unroll
      for (int kk = 0; kk < 2; ++kk) {
        const int slot = kk * 4 + lk;
        bfr[n][kk] =
            *(const bf16x8*)(ldsB + row * 128 + ((slot ^ (lr & 7)) << 4));
      }
    }
#pragma unroll
    for (int m = 0; m < 4; ++m)
#pragma unroll
      for (int n = 0; n < 4; ++n) {
        acc[m][n] = __builtin_amdgcn_mfma_f32_16x16x32_bf16(
            af[m][0], bfr[n][0], acc[m][n], 0, 0, 0);
        acc[m][n] = __builtin_amdgcn_mfma_f32_16x16x32_bf16(
            af[m][1], bfr[n][1], acc[m][n], 0, 0, 0);
      }

    if (more) {
      // drain AFTER compute (staging latency hidden under MFMA block);
      // raw barrier (no compiler-inserted early drain). ds_reads of
      // buf[cur] completed via compiler lgkmcnt before MFMAs -> next
      // iter's overwrite of buf[cur] is safe after this barrier.
      asm volatile("s_waitcnt vmcnt(0)" ::: "memory");
      __builtin_amdgcn_s_barrier();
    }
    cur ^= 1;
  }

  const int or0 = bm + wm * 64 + lk * 4;
  const int oc0 = bn + wn * 64 + lr;
#pragma unroll
  for (int m = 0; m < 4; ++m)
#pragma unroll
    for (int n = 0; n < 4; ++n)
#pragma unroll
      for (int r = 0; r < 4; ++r) {
        float v = acc[m][n][r];
        const size_t off = (size_t)(or0 + m * 16 + r) * N + (oc0 + n * 16);
        if (SPLITK > 1) {
          ((bf16_t*)Cout)[bz * MN + off] = (bf16_t)v;
        } else {
          if (RELU) v = fmaxf(v, 0.f);
          if (ADDBF16)
            ((float*)Cout)[off] = v + (float)add[off];
          else
            ((bf16_t*)Cout)[off] = (bf16_t)v;
        }
      }
}

// reduce NPART bf16 partials -> relu -> bf16
template <int NPART>
__global__ __launch_bounds__(256) void reduceN_kernel(
    const bf16_t* __restrict__ p, bf16_t* __restrict__ out, int n8,
    size_t MN) {
  int i = blockIdx.x * 256 + threadIdx.x;
  if (i >= n8) return;
  float s[8] = {};
#pragma unroll
  for (int z = 0; z < NPART; ++z) {
    bf16x8 v = *(const bf16x8*)(p + z * MN + (size_t)i * 8);
#pragma unroll
    for (int j = 0; j < 8; ++j) s[j] += (float)v[j];
  }
  bf16x8 o;
#pragma unroll
  for (int j = 0; j < 8; ++j) o[j] = (bf16_t)fmaxf(s[j], 0.f);
  *(bf16x8*)(out + (size_t)i * 8) = o;
}

// ---------------------------------------------------------------------------
// prep_all: enc->bf16 cvt + 4 weight transposes + w1r reorder (R12-proven).
// ---------------------------------------------------------------------------
__global__ __launch_bounds__(256) void prep_all(
    const float* __restrict__ enc, const float* __restrict__ Wcomp,
    const float* __restrict__ Wou1, const float* __restrict__ Wofc,
    const float* __restrict__ Wdec, const float* __restrict__ w1,
    bf16_t* __restrict__ encb, bf16_t* __restrict__ WcompT,
    bf16_t* __restrict__ Wou1T, bf16_t* __restrict__ WofcT,
    bf16_t* __restrict__ WdecT, float* __restrict__ w1r) {
  __shared__ float t[32][33];
  const int tid = threadIdx.x;
  int blk = blockIdx.x;

  if (blk < 12800) {
    const int i = blk * 256 + tid;
    float4 v = ((const float4*)enc)[i];
    bf16x4 o = {(bf16_t)v.x, (bf16_t)v.y, (bf16_t)v.z, (bf16_t)v.w};
    ((bf16x4*)encb)[i] = o;
    return;
  }
  blk -= 12800;

  const float* in;
  bf16_t* out;
  int K, N, nx;
  if (blk < 4096) {
    in = Wcomp; out = WcompT; K = 4096; N = 1024; nx = 32;
  } else if (blk < 5120) {
    blk -= 4096;
    in = Wou1; out = Wou1T; K = 1024; N = 1024; nx = 32;
  } else if (blk < 6144) {
    blk -= 5120;
    in = Wofc; out = WofcT; K = 1024; N = 1024; nx = 32;
  } else if (blk < 10240) {
    blk -= 6144;
    in = Wdec; out = WdecT; K = 1024; N = 4096; nx = 128;
  } else {  // w1r reorder
    blk -= 10240;
    const int idx = blk * 256 + tid;
    if (idx < NRCH * 90) {
      int ci = idx / 90, r = idx % 90, k9 = r / 10, co = r % 10;
      w1r[idx] = w1[((co * NRCH + ci) * 3 + k9 / 3) * 3 + (k9 % 3)];
    }
    return;
  }

  const int n0 = (blk % nx) * 32, k0 = (blk / nx) * 32;
  const int tx = tid & 31, ty = tid >> 5;
#pragma unroll
  for (int i = 0; i < 4; ++i)
    t[ty + i * 8][tx] = in[(size_t)(k0 + ty + i * 8) * N + n0 + tx];
  __syncthreads();
#pragma unroll
  for (int i = 0; i < 4; ++i)
    out[(size_t)(n0 + ty + i * 8) * K + k0 + tx] = (bf16_t)t[tx][ty + i * 8];
}

// ---------------------------------------------------------------------------
// femb1b (R15-proven): per-pair conv1 projection in BF16, slice padded to
// 16 elems: femb1b[p][k9][16]. Table 6.57 MB; elems 10..15 zero-filled.
// ---------------------------------------------------------------------------
__global__ __launch_bounds__(128) void femb1_kernel(
    const float* __restrict__ femb, const float* __restrict__ w1r,
    bf16_t* __restrict__ femb1b) {
  __shared__ float row[NRCH];
  const int p = blockIdx.x;
  const int t = threadIdx.x;
  if (t < NRCH) row[t] = femb[(size_t)p * NRCH + t];
  __syncthreads();
  for (int z = t; z < 54; z += 128)
    femb1b[((size_t)p * 9 + z / 6) * 16 + 10 + z % 6] = (bf16_t)0.f;
  if (t >= 90) return;
  float acc = 0.f;
#pragma unroll
  for (int ci = 0; ci < NRCH; ++ci) acc += row[ci] * w1r[ci * 90 + t];
  femb1b[((size_t)p * 9 + t / 10) * 16 + (t % 10)] = (bf16_t)acc;
}

// ---------------------------------------------------------------------------
// conv_fused (R15-proven, bf16 gather): conv1-gather + conv2/3+tanh.
// ---------------------------------------------------------------------------
__global__ __launch_bounds__(256) void conv_fused(
    const int* __restrict__ preds, const bf16_t* __restrict__ femb1b,
    const float* __restrict__ w2, const float* __restrict__ w3,
    float* __restrict__ adj) {
  __shared__ float xt[18][18][12];
  __shared__ float w[90];
  const int tid = threadIdx.x;
  const int b = blockIdx.z;
  const int ti = blockIdx.y * 16, tj = blockIdx.x * 16;

  if (tid < 90) {
    const int k9 = tid / 10, c2 = tid % 10;
    float a = 0.f;
#pragma unroll
    for (int c3 = 0; c3 < 5; ++c3) a += w3[c3] * w2[(c3 * 10 + c2) * 9 + k9];
    w[tid] = a;
  }

  const int* pr = preds + b * NOBJ;

  for (int t = tid; t < 324; t += 256) {
    const int hi = t / 18, wj = t % 18;
    const int ii = ti - 1 + hi, jj = tj - 1 + wj;
    float a[12] = {};
    if (ii >= 0 && ii < NOBJ && jj >= 0 && jj < NOBJ) {
#pragma unroll
      for (int kh = 0; kh < 3; ++kh) {
        const int i2 = ii + kh - 1;
        if (i2 < 0 || i2 >= NOBJ) continue;
        const int li = pr[i2];
#pragma unroll
        for (int kw = 0; kw < 3; ++kw) {
          const int j2 = jj + kw - 1;
          if (j2 < 0 || j2 >= NOBJ) continue;
          const int p = li * NCC + pr[j2];
          const bf16_t* f = femb1b + ((size_t)p * 9 + kh * 3 + kw) * 16;
          bf16x8 v0 = *(const bf16x8*)f;
          bf16x4 v1 = *(const bf16x4*)(f + 8);
#pragma unroll
          for (int c = 0; c < 8; ++c) a[c] += (float)v0[c];
#pragma unroll
          for (int c = 0; c < 2; ++c) a[8 + c] += (float)v1[c];
        }
      }
    }
    f32x4* o = (f32x4*)&xt[hi][wj][0];
    o[0] = (f32x4){a[0], a[1], a[2], a[3]};
    o[1] = (f32x4){a[4], a[5], a[6], a[7]};
    o[2] = (f32x4){a[8], a[9], 0.f, 0.f};
  }
  __syncthreads();

  const int di = tid >> 4, dj = tid & 15;
  const int i = ti + di, j = tj + dj;
  if (i >= NOBJ || j >= NOBJ) return;
  float acc = 0.f;
#pragma unroll
  for (int kh = 0; kh < 3; ++kh)
#pragma unroll
    for (int kw = 0; kw < 3; ++kw) {
      const float* xr = &xt[di + kh][dj + kw][0];
      const float* wr = w + (kh * 3 + kw) * 10;
#pragma unroll
      for (int c = 0; c < 10; ++c) acc += wr[c] * xr[c];
    }
  adj[((size_t)b * NOBJ + i) * NOBJ + j] = tanhf(acc);
}

// ---------------------------------------------------------------------------
// einsum via MFMA: ofl_u[b] = adj[b] (100x100) @ u1[b] (100x1024)
// (R4-proven; swizzled LDS transpose-on-stage, K padded to 128, zeroed)
// ---------------------------------------------------------------------------
__global__ __launch_bounds__(256) void einsum_mfma_kernel(
    const float* __restrict__ adj, const bf16_t* __restrict__ u1,
    bf16_t* __restrict__ ofl) {
  __shared__ __align__(16) bf16_t As[128 * 128];
  __shared__ __align__(16) bf16_t Us[128 * 128];
  const int b = blockIdx.y;
  const int h0 = blockIdx.x * 128;
  const int tid = threadIdx.x, lane = tid & 63, w = tid >> 6;
  const int wm = w >> 1, wn = w & 1;
  const int lr = lane & 15, lk = lane >> 4;

  {
    f32x4 z = {0.f, 0.f, 0.f, 0.f};
#pragma unroll
    for (int i = 0; i < 8; ++i) ((f32x4*)As)[tid + i * 256] = z;
#pragma unroll
    for (int i = 0; i < 8; ++i) ((f32x4*)Us)[tid + i * 256] = z;
  }
  __syncthreads();

  const float* ab = adj + (size_t)b * 10000;
#pragma unroll
  for (int i = 0; i < 10; ++i) {
    int idx = tid + i * 256;
    if (idx < 2500) {
      int row = idx / 25, kc = idx % 25;
      f32x4 v = ((const f32x4*)ab)[idx];
      bf16x4 o = {(bf16_t)v[0], (bf16_t)v[1], (bf16_t)v[2], (bf16_t)v[3]};
      int slot = kc >> 1;
      *(bf16x4*)((char*)As + row * 256 + ((slot ^ (row & 7)) << 4) +
                 (kc & 1) * 8) = o;
    }
  }

  const bf16_t* ub = u1 + (size_t)b * 100 * HDIM + h0;
#pragma unroll
  for (int i = 0; i < 7; ++i) {
    int idx = tid + i * 256;
    if (idx < 1600) {
      int hc = idx / 100, m = idx % 100;
      bf16x8 v = *(const bf16x8*)(ub + (size_t)m * HDIM + hc * 8);
      int slot = m >> 3, mr = m & 7;
#pragma unroll
      for (int j = 0; j < 8; ++j) {
        int h = hc * 8 + j;
        *((bf16_t*)((char*)Us + h * 256 + ((slot ^ (h & 7)) << 4) + mr * 2)) =
            v[j];
      }
    }
  }
  __syncthreads();

  f32x4 acc[4][4];
#pragma unroll
  for (int m = 0; m < 4; ++m)
#pragma unroll
    for (int n = 0; n < 4; ++n) acc[m][n] = (f32x4){0.f, 0.f, 0.f, 0.f};

#pragma unroll
  for (int ks = 0; ks < 4; ++ks) {
    bf16x8 a[4], u[4];
#pragma unroll
    for (int m = 0; m < 4; ++m) {
      int row = wm * 64 + m * 16 + lr;
      int slot = ks * 4 + lk;
      a[m] = *(const bf16x8*)((char*)As + row * 256 + ((slot ^ (lr & 7)) << 4));
    }
#pragma unroll
    for (int n = 0; n < 4; ++n) {
      int row = wn * 64 + n * 16 + lr;
      int slot = ks * 4 + lk;
      u[n] = *(const bf16x8*)((char*)Us + row * 256 + ((slot ^ (lr & 7)) << 4));
    }
#pragma unroll
    for (int m = 0; m < 4; ++m)
#pragma unroll
      for (int n = 0; n < 4; ++n)
        acc[m][n] = __builtin_amdgcn_mfma_f32_16x16x32_bf16(a[m], u[n],
                                                            acc[m][n], 0, 0, 0);
  }

  const int or0 = wm * 64 + lk * 4;
  const int oc0 = h0 + wn * 64 + lr;
#pragma unroll
  for (int m = 0; m < 4; ++m)
#pragma unroll
    for (int n = 0; n < 4; ++n)
#pragma unroll
      for (int r = 0; r < 4; ++r) {
        int row = or0 + m * 16 + r;
        if (row < 100)
          ofl[((size_t)b * 100 + row) * HDIM + oc0 + n * 16] =
              (bf16_t)acc[m][n][r];
      }
}

// ---------------------------------------------------------------------------
extern "C" void kernel_launch(void* const* d_in, const int* in_sizes, int n_in,
                              void* d_out, int out_size, void* d_ws,
                              size_t ws_size, hipStream_t stream) {
  const float* enc = (const float*)d_in[0];
  const float* W_comp = (const float*)d_in[1];
  const float* W_ou1 = (const float*)d_in[2];
  const float* W_ofc = (const float*)d_in[3];
  const float* W_dec = (const float*)d_in[4];
  const float* conv1w = (const float*)d_in[5];
  const float* conv2w = (const float*)d_in[6];
  const float* conv3w = (const float*)d_in[7];
  const float* femb = (const float*)d_in[8];
  const int* preds = (const int*)d_in[9];
  float* out = (float*)d_out;
  char* wsb = (char*)d_ws;

  const size_t MN = (size_t)TDIM * HDIM;  // 3,276,800

  // workspace (bytes), peak 87.8MB (<= 92.3MB proven R1). Same as R15.
  bf16_t* encb   = (bf16_t*)(wsb + 0);           // 26,214,400
  bf16_t* WcompT = (bf16_t*)(wsb + 26214400);    //  8,388,608 (ends 34.60M)
  bf16_t* Wou1T  = (bf16_t*)(wsb + 34603008);    //  2,097,152 (ends 36.70M)
  bf16_t* WofcT  = (bf16_t*)(wsb + 36700160);    //  2,097,152 (ends 38.80M)
  bf16_t* WdecT  = (bf16_t*)(wsb + 38797312);    //  8,388,608 (ends 47.19M)
  bf16_t* comp   = (bf16_t*)(wsb + 47185920);    //  6,553,600 (ends 53.74M)
  bf16_t* part4  = (bf16_t*)(wsb + 53739520);    // 26,214,400 (ends 79.95M)
  bf16_t* femb1b = (bf16_t*)(wsb + 79953920);    //  6,566,688 (ends 86.52M)
  float*  w1r    = (float*)(wsb + 86520608);     //     18,360 (ends 86.54M)
  float*  adj    = (float*)(wsb + 86540288);     //  1,280,000 (ends 87.82M)
  bf16_t* obj_u1 = (bf16_t*)(wsb + 53739520);    //  6,553,600 (after reduce4)
  bf16_t* u_m    = (bf16_t*)(wsb + 60293120);    //  6,553,600 (ends 66.85M)
  bf16_t* ofl_u  = (bf16_t*)(wsb + 47185920);    //  6,553,600 (over comp)

  const int n8 = (int)(MN / 8);  // 409,600 -> 1600 blocks for reduceN

  // 0. conversions + w1r (1 launch)
  prep_all<<<23058, 256, 0, stream>>>(enc, W_comp, W_ou1, W_ofc, W_dec,
                                      conv1w, encb, WcompT, Wou1T, WofcT,
                                      WdecT, w1r);

  // 1. G1: comp partials, split-4 MODE3 (832 blocks) + reduce4
  gemm_bf16<false, false, 4, 3><<<dim3(832, 1, 1), 256, 0, stream>>>(
      encb, WcompT, nullptr, part4, HDIM, DDIM, MN);
  reduceN_kernel<4><<<n8 / 256, 256, 0, stream>>>(part4, comp, n8, MN);

  // 2. obj_u1 = relu(comp @ W_ou1)
  gemm_bf16<true, false, 1, 0>
      <<<dim3(HDIM / 128, TDIM / 128), 256, 0, stream>>>(
          comp, Wou1T, nullptr, obj_u1, HDIM, HDIM, MN);

  // 3. conv chain: femb1 (bf16 table) + fused conv
  femb1_kernel<<<NPAIR, 128, 0, stream>>>(femb, w1r, femb1b);
  conv_fused<<<dim3(7, 7, BDIM), 256, 0, stream>>>(preds, femb1b, conv2w,
                                                   conv3w, adj);

  // 4. einsum via MFMA -> ofl_u
  einsum_mfma_kernel<<<dim3(HDIM / 128, BDIM), 256, 0, stream>>>(adj, obj_u1,
                                                                 ofl_u);

  // 5. u_m = relu(ofl_u @ W_ofc)
  gemm_bf16<true, false, 1, 0>
      <<<dim3(HDIM / 128, TDIM / 128), 256, 0, stream>>>(
          ofl_u, WofcT, nullptr, u_m, HDIM, HDIM, MN);

  // 6. out = relu(u_m @ W_dec) + enc(bf16)  (fp32 out)
  gemm_bf16<true, true, 1, 0>
      <<<dim3(DDIM / 128, TDIM / 128), 256, 0, stream>>>(
          u_m, WdecT, encb, out, DDIM, HDIM, MN);
}

// Round 17
// 232.927 us; speedup vs baseline: 1.0374x; 1.0374x over previous
//
#include <hip/hip_runtime.h>
#include <cmath>

#define NCC 151
#define NRCH 51
#define BDIM 32
#define NOBJ 100
#define DDIM 4096
#define HDIM 1024
#define TDIM (BDIM * NOBJ)   // 3200
#define NPAIR (NCC * NCC)    // 22801

typedef __bf16 bf16_t;
typedef __bf16 bf16x8 __attribute__((ext_vector_type(8)));
typedef __bf16 bf16x4 __attribute__((ext_vector_type(4)));
typedef float f32x4 __attribute__((ext_vector_type(4)));

// ---------------------------------------------------------------------------
// bf16 MFMA GEMM (R8/R15-proven single-buffer): C = act(A @ Bt^T) (+ add)
// 128x128 tile, BK=64, 256 threads = 4 waves (2x2), 16x16x32 MFMA.
// XOR-swizzled LDS. MODE 0: bijective XCD-chunk swizzle (nwg % 8 == 0).
// MODE 3 (G1, SPLITK=4, grid 832 flat): XCD-pair owns one K=1024 plane.
// SPLITK>1: bf16 partial to Cout + bz*MN. ADDBF16: fp32 out = relu + add.
// NOTE: dbuf (R10/R16) and 256^2 (R11) variants measured SLOWER — the
// 32 KB single-buffer maximizes resident blocks, which dominates here.
// ---------------------------------------------------------------------------
template <bool RELU, bool ADDBF16, int SPLITK, int MODE>
__global__ __launch_bounds__(256) void gemm_bf16(
    const bf16_t* __restrict__ A, const bf16_t* __restrict__ Bt,
    const bf16_t* __restrict__ add, void* __restrict__ Cout,
    int N, int K, size_t MN) {
  __shared__ __align__(16) bf16_t Asm[128 * 64];
  __shared__ __align__(16) bf16_t Bsm[128 * 64];
  const int tid = threadIdx.x;
  const int lane = tid & 63;
  const int w = tid >> 6;
  const int wm = w >> 1, wn = w & 1;

  const int nx = gridDim.x, ny = gridDim.y, nz = gridDim.z;
  const int h = blockIdx.x + nx * (blockIdx.y + ny * blockIdx.z);
  int bx, by, bz;
  if (MODE == 3) {
    const int xcd = h & 7, s = h >> 3;   // s in [0,104)
    bz = xcd >> 1;
    const int half = xcd & 1;
    if (half == 1 && s >= 96) return;    // idle pad blocks (block-uniform)
    const int c = s / 40;
    if (c < 2) {
      const int within = s % 40;
      bx = within / 5;
      by = (half ? 13 : 0) + c * 5 + within % 5;
    } else if (half == 0) {
      const int w2 = s - 80;
      bx = w2 / 3;
      by = 10 + w2 % 3;
    } else {
      const int w2 = s - 80;
      bx = w2 / 2;
      by = 23 + w2 % 2;
    }
  } else {
    const int nwg = nx * ny * nz;  // % 8 == 0
    const int q = nwg >> 3;
    const int lin = (h & 7) * q + (h >> 3);
    by = lin % ny;
    const int r = lin / ny;
    bx = r % nx;
    bz = r / nx;
  }

  const int bm = by * 128, bn = bx * 128;
  const int lr = lane & 15, lk = lane >> 4;

  int kBeg = 0, kEnd = K;
  if (SPLITK > 1) {
    const int chunk = (((K / 64) + SPLITK - 1) / SPLITK) * 64;
    kBeg = bz * chunk;
    kEnd = min(K, kBeg + chunk);
  }

  f32x4 acc[4][4];
#pragma unroll
  for (int m = 0; m < 4; ++m)
#pragma unroll
    for (int n = 0; n < 4; ++n) acc[m][n] = (f32x4){0.f, 0.f, 0.f, 0.f};

  const int srow = tid >> 3, sslot = tid & 7;
  char* ldsA = (char*)Asm;
  char* ldsB = (char*)Bsm;

  for (int kt = kBeg; kt < kEnd; kt += 64) {
    __syncthreads();
#pragma unroll
    for (int i = 0; i < 4; ++i) {
      const int row = i * 32 + srow;
      const int kc = sslot ^ (row & 7);
      const bf16_t* ga = A + (size_t)(bm + row) * K + kt + kc * 8;
      const bf16_t* gb = Bt + (size_t)(bn + row) * K + kt + kc * 8;
      __builtin_amdgcn_global_load_lds(
          (const __attribute__((address_space(1))) void*)ga,
          (__attribute__((address_space(3))) void*)(ldsA + i * 4096 + w * 1024),
          16, 0, 0);
      __builtin_amdgcn_global_load_lds(
          (const __attribute__((address_space(1))) void*)gb,
          (__attribute__((address_space(3))) void*)(ldsB + i * 4096 + w * 1024),
          16, 0, 0);
    }
    __syncthreads();

    bf16x8 af[4][2], bfr[4][2];
#pragma unroll
    for (int m = 0; m < 4; ++m) {
      const int row = wm * 64 + m * 16 + lr;
#pragma unroll
      for (int kk = 0; kk < 2; ++kk) {
        const int slot = kk * 4 + lk;
        af[m][kk] =
            *(const bf16x8*)(ldsA + row * 128 + ((slot ^ (lr & 7)) << 4));
      }
    }
#pragma unroll
    for (int n = 0; n < 4; ++n) {
      const int row = wn * 64 + n * 16 + lr;
#pragma unroll
      for (int kk = 0; kk < 2; ++kk) {
        const int slot = kk * 4 + lk;
        bfr[n][kk] =
            *(const bf16x8*)(ldsB + row * 128 + ((slot ^ (lr & 7)) << 4));
      }
    }
#pragma unroll
    for (int m = 0; m < 4; ++m)
#pragma unroll
      for (int n = 0; n < 4; ++n) {
        acc[m][n] = __builtin_amdgcn_mfma_f32_16x16x32_bf16(
            af[m][0], bfr[n][0], acc[m][n], 0, 0, 0);
        acc[m][n] = __builtin_amdgcn_mfma_f32_16x16x32_bf16(
            af[m][1], bfr[n][1], acc[m][n], 0, 0, 0);
      }
  }

  const int or0 = bm + wm * 64 + lk * 4;
  const int oc0 = bn + wn * 64 + lr;
#pragma unroll
  for (int m = 0; m < 4; ++m)
#pragma unroll
    for (int n = 0; n < 4; ++n)
#pragma unroll
      for (int r = 0; r < 4; ++r) {
        float v = acc[m][n][r];
        const size_t off = (size_t)(or0 + m * 16 + r) * N + (oc0 + n * 16);
        if (SPLITK > 1) {
          ((bf16_t*)Cout)[bz * MN + off] = (bf16_t)v;
        } else {
          if (RELU) v = fmaxf(v, 0.f);
          if (ADDBF16)
            ((float*)Cout)[off] = v + (float)add[off];
          else
            ((bf16_t*)Cout)[off] = (bf16_t)v;
        }
      }
}

// reduce NPART bf16 partials -> relu -> bf16
template <int NPART>
__global__ __launch_bounds__(256) void reduceN_kernel(
    const bf16_t* __restrict__ p, bf16_t* __restrict__ out, int n8,
    size_t MN) {
  int i = blockIdx.x * 256 + threadIdx.x;
  if (i >= n8) return;
  float s[8] = {};
#pragma unroll
  for (int z = 0; z < NPART; ++z) {
    bf16x8 v = *(const bf16x8*)(p + z * MN + (size_t)i * 8);
#pragma unroll
    for (int j = 0; j < 8; ++j) s[j] += (float)v[j];
  }
  bf16x8 o;
#pragma unroll
  for (int j = 0; j < 8; ++j) o[j] = (bf16_t)fmaxf(s[j], 0.f);
  *(bf16x8*)(out + (size_t)i * 8) = o;
}

// ---------------------------------------------------------------------------
// prep_all: enc->bf16 cvt + 4 weight transposes + w1r reorder (R12-proven).
// ---------------------------------------------------------------------------
__global__ __launch_bounds__(256) void prep_all(
    const float* __restrict__ enc, const float* __restrict__ Wcomp,
    const float* __restrict__ Wou1, const float* __restrict__ Wofc,
    const float* __restrict__ Wdec, const float* __restrict__ w1,
    bf16_t* __restrict__ encb, bf16_t* __restrict__ WcompT,
    bf16_t* __restrict__ Wou1T, bf16_t* __restrict__ WofcT,
    bf16_t* __restrict__ WdecT, float* __restrict__ w1r) {
  __shared__ float t[32][33];
  const int tid = threadIdx.x;
  int blk = blockIdx.x;

  if (blk < 12800) {
    const int i = blk * 256 + tid;
    float4 v = ((const float4*)enc)[i];
    bf16x4 o = {(bf16_t)v.x, (bf16_t)v.y, (bf16_t)v.z, (bf16_t)v.w};
    ((bf16x4*)encb)[i] = o;
    return;
  }
  blk -= 12800;

  const float* in;
  bf16_t* out;
  int K, N, nx;
  if (blk < 4096) {
    in = Wcomp; out = WcompT; K = 4096; N = 1024; nx = 32;
  } else if (blk < 5120) {
    blk -= 4096;
    in = Wou1; out = Wou1T; K = 1024; N = 1024; nx = 32;
  } else if (blk < 6144) {
    blk -= 5120;
    in = Wofc; out = WofcT; K = 1024; N = 1024; nx = 32;
  } else if (blk < 10240) {
    blk -= 6144;
    in = Wdec; out = WdecT; K = 1024; N = 4096; nx = 128;
  } else {  // w1r reorder
    blk -= 10240;
    const int idx = blk * 256 + tid;
    if (idx < NRCH * 90) {
      int ci = idx / 90, r = idx % 90, k9 = r / 10, co = r % 10;
      w1r[idx] = w1[((co * NRCH + ci) * 3 + k9 / 3) * 3 + (k9 % 3)];
    }
    return;
  }

  const int n0 = (blk % nx) * 32, k0 = (blk / nx) * 32;
  const int tx = tid & 31, ty = tid >> 5;
#pragma unroll
  for (int i = 0; i < 4; ++i)
    t[ty + i * 8][tx] = in[(size_t)(k0 + ty + i * 8) * N + n0 + tx];
  __syncthreads();
#pragma unroll
  for (int i = 0; i < 4; ++i)
    out[(size_t)(n0 + ty + i * 8) * K + k0 + tx] = (bf16_t)t[tx][ty + i * 8];
}

// ---------------------------------------------------------------------------
// femb1b (R15-proven): per-pair conv1 projection in BF16, slice padded to
// 16 elems: femb1b[p][k9][16]. Table 6.57 MB; elems 10..15 zero-filled.
// ---------------------------------------------------------------------------
__global__ __launch_bounds__(128) void femb1_kernel(
    const float* __restrict__ femb, const float* __restrict__ w1r,
    bf16_t* __restrict__ femb1b) {
  __shared__ float row[NRCH];
  const int p = blockIdx.x;
  const int t = threadIdx.x;
  if (t < NRCH) row[t] = femb[(size_t)p * NRCH + t];
  __syncthreads();
  for (int z = t; z < 54; z += 128)
    femb1b[((size_t)p * 9 + z / 6) * 16 + 10 + z % 6] = (bf16_t)0.f;
  if (t >= 90) return;
  float acc = 0.f;
#pragma unroll
  for (int ci = 0; ci < NRCH; ++ci) acc += row[ci] * w1r[ci * 90 + t];
  femb1b[((size_t)p * 9 + t / 10) * 16 + (t % 10)] = (bf16_t)acc;
}

// ---------------------------------------------------------------------------
// conv_fused (R15-proven, bf16 gather): conv1-gather + conv2/3+tanh.
// Block = (b, 16x16 tile). Phase 1: 18x18 halo of x1 in LDS (fp32 accum
// from bf16 slices). Phase 2: 3x3 x 10ch contraction + tanh.
// ---------------------------------------------------------------------------
__global__ __launch_bounds__(256) void conv_fused(
    const int* __restrict__ preds, const bf16_t* __restrict__ femb1b,
    const float* __restrict__ w2, const float* __restrict__ w3,
    float* __restrict__ adj) {
  __shared__ float xt[18][18][12];
  __shared__ float w[90];
  const int tid = threadIdx.x;
  const int b = blockIdx.z;
  const int ti = blockIdx.y * 16, tj = blockIdx.x * 16;

  if (tid < 90) {
    const int k9 = tid / 10, c2 = tid % 10;
    float a = 0.f;
#pragma unroll
    for (int c3 = 0; c3 < 5; ++c3) a += w3[c3] * w2[(c3 * 10 + c2) * 9 + k9];
    w[tid] = a;
  }

  const int* pr = preds + b * NOBJ;

  for (int t = tid; t < 324; t += 256) {
    const int hi = t / 18, wj = t % 18;
    const int ii = ti - 1 + hi, jj = tj - 1 + wj;
    float a[12] = {};
    if (ii >= 0 && ii < NOBJ && jj >= 0 && jj < NOBJ) {
#pragma unroll
      for (int kh = 0; kh < 3; ++kh) {
        const int i2 = ii + kh - 1;
        if (i2 < 0 || i2 >= NOBJ) continue;
        const int li = pr[i2];
#pragma unroll
        for (int kw = 0; kw < 3; ++kw) {
          const int j2 = jj + kw - 1;
          if (j2 < 0 || j2 >= NOBJ) continue;
          const int p = li * NCC + pr[j2];
          const bf16_t* f = femb1b + ((size_t)p * 9 + kh * 3 + kw) * 16;
          bf16x8 v0 = *(const bf16x8*)f;
          bf16x4 v1 = *(const bf16x4*)(f + 8);
#pragma unroll
          for (int c = 0; c < 8; ++c) a[c] += (float)v0[c];
#pragma unroll
          for (int c = 0; c < 2; ++c) a[8 + c] += (float)v1[c];
        }
      }
    }
    f32x4* o = (f32x4*)&xt[hi][wj][0];
    o[0] = (f32x4){a[0], a[1], a[2], a[3]};
    o[1] = (f32x4){a[4], a[5], a[6], a[7]};
    o[2] = (f32x4){a[8], a[9], 0.f, 0.f};
  }
  __syncthreads();

  const int di = tid >> 4, dj = tid & 15;
  const int i = ti + di, j = tj + dj;
  if (i >= NOBJ || j >= NOBJ) return;
  float acc = 0.f;
#pragma unroll
  for (int kh = 0; kh < 3; ++kh)
#pragma unroll
    for (int kw = 0; kw < 3; ++kw) {
      const float* xr = &xt[di + kh][dj + kw][0];
      const float* wr = w + (kh * 3 + kw) * 10;
#pragma unroll
      for (int c = 0; c < 10; ++c) acc += wr[c] * xr[c];
    }
  adj[((size_t)b * NOBJ + i) * NOBJ + j] = tanhf(acc);
}

// ---------------------------------------------------------------------------
// einsum via MFMA: ofl_u[b] = adj[b] (100x100) @ u1[b] (100x1024)
// (R4-proven; swizzled LDS transpose-on-stage, K padded to 128, zeroed)
// ---------------------------------------------------------------------------
__global__ __launch_bounds__(256) void einsum_mfma_kernel(
    const float* __restrict__ adj, const bf16_t* __restrict__ u1,
    bf16_t* __restrict__ ofl) {
  __shared__ __align__(16) bf16_t As[128 * 128];
  __shared__ __align__(16) bf16_t Us[128 * 128];
  const int b = blockIdx.y;
  const int h0 = blockIdx.x * 128;
  const int tid = threadIdx.x, lane = tid & 63, w = tid >> 6;
  const int wm = w >> 1, wn = w & 1;
  const int lr = lane & 15, lk = lane >> 4;

  {
    f32x4 z = {0.f, 0.f, 0.f, 0.f};
#pragma unroll
    for (int i = 0; i < 8; ++i) ((f32x4*)As)[tid + i * 256] = z;
#pragma unroll
    for (int i = 0; i < 8; ++i) ((f32x4*)Us)[tid + i * 256] = z;
  }
  __syncthreads();

  const float* ab = adj + (size_t)b * 10000;
#pragma unroll
  for (int i = 0; i < 10; ++i) {
    int idx = tid + i * 256;
    if (idx < 2500) {
      int row = idx / 25, kc = idx % 25;
      f32x4 v = ((const f32x4*)ab)[idx];
      bf16x4 o = {(bf16_t)v[0], (bf16_t)v[1], (bf16_t)v[2], (bf16_t)v[3]};
      int slot = kc >> 1;
      *(bf16x4*)((char*)As + row * 256 + ((slot ^ (row & 7)) << 4) +
                 (kc & 1) * 8) = o;
    }
  }

  const bf16_t* ub = u1 + (size_t)b * 100 * HDIM + h0;
#pragma unroll
  for (int i = 0; i < 7; ++i) {
    int idx = tid + i * 256;
    if (idx < 1600) {
      int hc = idx / 100, m = idx % 100;
      bf16x8 v = *(const bf16x8*)(ub + (size_t)m * HDIM + hc * 8);
      int slot = m >> 3, mr = m & 7;
#pragma unroll
      for (int j = 0; j < 8; ++j) {
        int h = hc * 8 + j;
        *((bf16_t*)((char*)Us + h * 256 + ((slot ^ (h & 7)) << 4) + mr * 2)) =
            v[j];
      }
    }
  }
  __syncthreads();

  f32x4 acc[4][4];
#pragma unroll
  for (int m = 0; m < 4; ++m)
#pragma unroll
    for (int n = 0; n < 4; ++n) acc[m][n] = (f32x4){0.f, 0.f, 0.f, 0.f};

#pragma unroll
  for (int ks = 0; ks < 4; ++ks) {
    bf16x8 a[4], u[4];
#pragma unroll
    for (int m = 0; m < 4; ++m) {
      int row = wm * 64 + m * 16 + lr;
      int slot = ks * 4 + lk;
      a[m] = *(const bf16x8*)((char*)As + row * 256 + ((slot ^ (lr & 7)) << 4));
    }
#pragma unroll
    for (int n = 0; n < 4; ++n) {
      int row = wn * 64 + n * 16 + lr;
      int slot = ks * 4 + lk;
      u[n] = *(const bf16x8*)((char*)Us + row * 256 + ((slot ^ (lr & 7)) << 4));
    }
#pragma unroll
    for (int m = 0; m < 4; ++m)
#pragma unroll
      for (int n = 0; n < 4; ++n)
        acc[m][n] = __builtin_amdgcn_mfma_f32_16x16x32_bf16(a[m], u[n],
                                                            acc[m][n], 0, 0, 0);
  }

  const int or0 = wm * 64 + lk * 4;
  const int oc0 = h0 + wn * 64 + lr;
#pragma unroll
  for (int m = 0; m < 4; ++m)
#pragma unroll
    for (int n = 0; n < 4; ++n)
#pragma unroll
      for (int r = 0; r < 4; ++r) {
        int row = or0 + m * 16 + r;
        if (row < 100)
          ofl[((size_t)b * 100 + row) * HDIM + oc0 + n * 16] =
              (bf16_t)acc[m][n][r];
      }
}

// ---------------------------------------------------------------------------
extern "C" void kernel_launch(void* const* d_in, const int* in_sizes, int n_in,
                              void* d_out, int out_size, void* d_ws,
                              size_t ws_size, hipStream_t stream) {
  const float* enc = (const float*)d_in[0];
  const float* W_comp = (const float*)d_in[1];
  const float* W_ou1 = (const float*)d_in[2];
  const float* W_ofc = (const float*)d_in[3];
  const float* W_dec = (const float*)d_in[4];
  const float* conv1w = (const float*)d_in[5];
  const float* conv2w = (const float*)d_in[6];
  const float* conv3w = (const float*)d_in[7];
  const float* femb = (const float*)d_in[8];
  const int* preds = (const int*)d_in[9];
  float* out = (float*)d_out;
  char* wsb = (char*)d_ws;

  const size_t MN = (size_t)TDIM * HDIM;  // 3,276,800

  // workspace (bytes), peak 87.8MB (<= 92.3MB proven R1). Same as R15.
  bf16_t* encb   = (bf16_t*)(wsb + 0);           // 26,214,400
  bf16_t* WcompT = (bf16_t*)(wsb + 26214400);    //  8,388,608 (ends 34.60M)
  bf16_t* Wou1T  = (bf16_t*)(wsb + 34603008);    //  2,097,152 (ends 36.70M)
  bf16_t* WofcT  = (bf16_t*)(wsb + 36700160);    //  2,097,152 (ends 38.80M)
  bf16_t* WdecT  = (bf16_t*)(wsb + 38797312);    //  8,388,608 (ends 47.19M)
  bf16_t* comp   = (bf16_t*)(wsb + 47185920);    //  6,553,600 (ends 53.74M)
  bf16_t* part4  = (bf16_t*)(wsb + 53739520);    // 26,214,400 (ends 79.95M)
  bf16_t* femb1b = (bf16_t*)(wsb + 79953920);    //  6,566,688 (ends 86.52M)
  float*  w1r    = (float*)(wsb + 86520608);     //     18,360 (ends 86.54M)
  float*  adj    = (float*)(wsb + 86540288);     //  1,280,000 (ends 87.82M)
  bf16_t* obj_u1 = (bf16_t*)(wsb + 53739520);    //  6,553,600 (after reduce4)
  bf16_t* u_m    = (bf16_t*)(wsb + 60293120);    //  6,553,600 (ends 66.85M)
  bf16_t* ofl_u  = (bf16_t*)(wsb + 47185920);    //  6,553,600 (over comp)

  const int n8 = (int)(MN / 8);  // 409,600 -> 1600 blocks for reduceN

  // 0. conversions + w1r (1 launch)
  prep_all<<<23058, 256, 0, stream>>>(enc, W_comp, W_ou1, W_ofc, W_dec,
                                      conv1w, encb, WcompT, Wou1T, WofcT,
                                      WdecT, w1r);

  // 1. G1: comp partials, split-4 MODE3 (832 blocks) + reduce4
  gemm_bf16<false, false, 4, 3><<<dim3(832, 1, 1), 256, 0, stream>>>(
      encb, WcompT, nullptr, part4, HDIM, DDIM, MN);
  reduceN_kernel<4><<<n8 / 256, 256, 0, stream>>>(part4, comp, n8, MN);

  // 2. obj_u1 = relu(comp @ W_ou1)
  gemm_bf16<true, false, 1, 0>
      <<<dim3(HDIM / 128, TDIM / 128), 256, 0, stream>>>(
          comp, Wou1T, nullptr, obj_u1, HDIM, HDIM, MN);

  // 3. conv chain: femb1 (bf16 table) + fused conv
  femb1_kernel<<<NPAIR, 128, 0, stream>>>(femb, w1r, femb1b);
  conv_fused<<<dim3(7, 7, BDIM), 256, 0, stream>>>(preds, femb1b, conv2w,
                                                   conv3w, adj);

  // 4. einsum via MFMA -> ofl_u
  einsum_mfma_kernel<<<dim3(HDIM / 128, BDIM), 256, 0, stream>>>(adj, obj_u1,
                                                                 ofl_u);

  // 5. u_m = relu(ofl_u @ W_ofc)
  gemm_bf16<true, false, 1, 0>
      <<<dim3(HDIM / 128, TDIM / 128), 256, 0, stream>>>(
          ofl_u, WofcT, nullptr, u_m, HDIM, HDIM, MN);

  // 6. out = relu(u_m @ W_dec) + enc(bf16)  (fp32 out)
  gemm_bf16<true, true, 1, 0>
      <<<dim3(DDIM / 128, TDIM / 128), 256, 0, stream>>>(
          u_m, WdecT, encb, out, DDIM, HDIM, MN);
}